// Round 3
// baseline (128.447 us; speedup 1.0000x reference)
//
#include <hip/hip_runtime.h>

typedef __attribute__((ext_vector_type(8))) short short8;
typedef __attribute__((ext_vector_type(4))) float f32x4;

#define YSTR 1032   // LN scratch row stride (bf16): 16 x 1032
#define GSTR 1048   // G tile row stride (bf16)
#define TFS  40     // tf tile row stride (pad 32->40: conflict-free frag reads)
#define DFYS 132    // df LN row stride (pad 128->132)
#define DFBS 40     // df proj row stride

__device__ __forceinline__ unsigned short f2bf(float f) {
  union { float f; unsigned u; } v; v.f = f;
  unsigned r = v.u + 0x7FFFu + ((v.u >> 16) & 1u);  // RNE
  return (unsigned short)(r >> 16);
}
__device__ __forceinline__ unsigned pack2(float a, float b) {
  return (unsigned)f2bf(a) | ((unsigned)f2bf(b) << 16);
}
__device__ __forceinline__ short8 packW(float4 a, float4 b) {
  union { short8 s; unsigned u[4]; } r;
  r.u[0] = pack2(a.x, a.y); r.u[1] = pack2(a.z, a.w);
  r.u[2] = pack2(b.x, b.y); r.u[3] = pack2(b.z, b.w);
  return r.s;
}

// One fused kernel: 512 blocks = b(4) x n-tile16(32) x i-quarter(4), 256 threads.
// S1 LN(target tile)->Yl   S2 proj tf (MFMA, K split 4 waves)   S3 reduce->TFl
// S4 LN(drug b)->DFy       S5a proj df->DFb   S5b G=tf@W3 -> Gl
// S6 out = (G @ df^T + b_out)*mask  (float4 stores), + mask output.
__global__ __launch_bounds__(256) void k_fused(
    const float* __restrict__ tgt, const float* __restrict__ drg,
    const float* __restrict__ tmask, const float* __restrict__ dmask,
    const float* __restrict__ ln_t_g, const float* __restrict__ ln_t_b,
    const float* __restrict__ ln_d_g, const float* __restrict__ ln_d_b,
    const float* __restrict__ W_t, const float* __restrict__ b_t,
    const float* __restrict__ W_d, const float* __restrict__ b_d,
    const float* __restrict__ W_out, const float* __restrict__ b_out,
    float* __restrict__ out, float* __restrict__ mask_out)
{
  __shared__ union { unsigned short Yl[16 * YSTR]; unsigned short Gl[16 * GSTR]; } U1; // 33.5 KB
  __shared__ union { float pd[3 * 2 * 16 * 16]; unsigned short DFy[64 * DFYS]; } U2;   // 16.9 KB
  __shared__ unsigned short TFl[16 * TFS];   // 1.3 KB
  __shared__ unsigned short DFb[64 * DFBS];  // 5.1 KB

  const int id = blockIdx.x;
  const int b = id >> 7, n16 = (id >> 2) & 31, iq = id & 3;
  const int n0 = n16 * 16, i0 = iq * 32;
  const int tid = threadIdx.x, w = tid >> 6, lid = tid & 63, l = tid & 15, q = (tid >> 4) & 3;
  const f32x4 zero = {0.f, 0.f, 0.f, 0.f};

  // ---- S1: LayerNorm target rows n0..n0+15 (wave w: rows w*4..w*4+3) -> Yl bf16
  #pragma unroll
  for (int rr = 0; rr < 4; ++rr) {
    const int row = w * 4 + rr;
    const float* xr = tgt + (size_t)(b * 512 + n0 + row) * 1024;
    float4 v[4];
    float s = 0.f, s2 = 0.f;
    #pragma unroll
    for (int k = 0; k < 4; ++k) {
      v[k] = *(const float4*)(xr + 4 * lid + 256 * k);
      s  += (v[k].x + v[k].y) + (v[k].z + v[k].w);
      s2 += (v[k].x * v[k].x + v[k].y * v[k].y) + (v[k].z * v[k].z + v[k].w * v[k].w);
    }
    #pragma unroll
    for (int off = 32; off >= 1; off >>= 1) { s += __shfl_xor(s, off, 64); s2 += __shfl_xor(s2, off, 64); }
    const float mu = s * (1.f / 1024.f);
    const float rs = rsqrtf(s2 * (1.f / 1024.f) - mu * mu + 1e-5f);
    #pragma unroll
    for (int k = 0; k < 4; ++k) {
      float4 gg = *(const float4*)(ln_t_g + 4 * lid + 256 * k);
      float4 bb = *(const float4*)(ln_t_b + 4 * lid + 256 * k);
      unsigned* yd = (unsigned*)(U1.Yl + row * YSTR + 4 * lid + 256 * k);
      yd[0] = pack2((v[k].x - mu) * rs * gg.x + bb.x, (v[k].y - mu) * rs * gg.y + bb.y);
      yd[1] = pack2((v[k].z - mu) * rs * gg.z + bb.z, (v[k].w - mu) * rs * gg.w + bb.w);
    }
  }
  __syncthreads();

  // ---- S2: tf projection, K=1024 split: wave w takes k-steps w*8..w*8+7, both h-tiles
  f32x4 acc0 = zero, acc1 = zero;
  #pragma unroll
  for (int ss = 0; ss < 8; ++ss) {
    const int s = w * 8 + ss;
    short8 af = *(const short8*)(U1.Yl + l * YSTR + s * 32 + q * 8);     // A[m=row][k=c]
    const float* wp0 = W_t + (size_t)l * 1024 + s * 32 + q * 8;          // h = l
    const float* wp1 = W_t + (size_t)(16 + l) * 1024 + s * 32 + q * 8;   // h = 16+l
    acc0 = __builtin_amdgcn_mfma_f32_16x16x32_bf16(af, packW(*(const float4*)wp0, *(const float4*)(wp0 + 4)), acc0, 0, 0, 0);
    acc1 = __builtin_amdgcn_mfma_f32_16x16x32_bf16(af, packW(*(const float4*)wp1, *(const float4*)(wp1 + 4)), acc1, 0, 0, 0);
  }
  if (w > 0) {
    #pragma unroll
    for (int r = 0; r < 4; ++r) {
      U2.pd[(w - 1) * 512 + (q * 4 + r) * 16 + l]       = acc0[r];
      U2.pd[(w - 1) * 512 + 256 + (q * 4 + r) * 16 + l] = acc1[r];
    }
  }
  __syncthreads();

  // ---- S3: wave 0 reduces partials, applies bias+mask, writes bf16 tf tile
  if (w == 0) {
    #pragma unroll
    for (int ht = 0; ht < 2; ++ht) {
      const int h = ht * 16 + l;
      const float pbv = b_t[h];
      #pragma unroll
      for (int r = 0; r < 4; ++r) {
        const int rl = q * 4 + r;
        float val = (ht ? acc1[r] : acc0[r]) + pbv;
        #pragma unroll
        for (int k = 0; k < 3; ++k) val += U2.pd[k * 512 + ht * 256 + rl * 16 + l];
        val *= tmask[b * 512 + n0 + rl];
        TFl[rl * TFS + h] = f2bf(val);
      }
    }
  }
  __syncthreads();   // TFl ready; pd dead (DFy may now overwrite)

  // ---- S4: LayerNorm drug rows (wave w: rows w*16..w*16+15) -> DFy bf16
  for (int rr = 0; rr < 16; ++rr) {
    const int m = w * 16 + rr;
    const float* xr = drg + (size_t)(b * 64 + m) * 128;
    float2 v = *(const float2*)(xr + 2 * lid);
    float s = v.x + v.y, s2 = v.x * v.x + v.y * v.y;
    #pragma unroll
    for (int off = 32; off >= 1; off >>= 1) { s += __shfl_xor(s, off, 64); s2 += __shfl_xor(s2, off, 64); }
    const float mu = s * (1.f / 128.f);
    const float rs = rsqrtf(s2 * (1.f / 128.f) - mu * mu + 1e-5f);
    float2 gg = *(const float2*)(ln_d_g + 2 * lid);
    float2 bb = *(const float2*)(ln_d_b + 2 * lid);
    *(unsigned*)(U2.DFy + m * DFYS + 2 * lid) =
        pack2((v.x - mu) * rs * gg.x + bb.x, (v.y - mu) * rs * gg.y + bb.y);
  }
  __syncthreads();

  // ---- S5a: df projection, wave w = m-tile w (rows w*16..w*16+15), K=128
  {
    f32x4 a0 = zero, a1 = zero;
    #pragma unroll
    for (int s = 0; s < 4; ++s) {
      short8 af = *(const short8*)(U2.DFy + (w * 16 + l) * DFYS + s * 32 + q * 8);
      const float* wp0 = W_d + (size_t)l * 128 + s * 32 + q * 8;
      const float* wp1 = W_d + (size_t)(16 + l) * 128 + s * 32 + q * 8;
      a0 = __builtin_amdgcn_mfma_f32_16x16x32_bf16(af, packW(*(const float4*)wp0, *(const float4*)(wp0 + 4)), a0, 0, 0, 0);
      a1 = __builtin_amdgcn_mfma_f32_16x16x32_bf16(af, packW(*(const float4*)wp1, *(const float4*)(wp1 + 4)), a1, 0, 0, 0);
    }
    #pragma unroll
    for (int ht = 0; ht < 2; ++ht) {
      const int h = ht * 16 + l;
      const float pbv = b_d[h];
      #pragma unroll
      for (int r = 0; r < 4; ++r) {
        const int m = w * 16 + q * 4 + r;
        float val = (ht ? a1[r] : a0[r]) + pbv;
        val *= dmask[b * 64 + m];
        DFb[m * DFBS + h] = f2bf(val);
      }
    }
  }

  // ---- S5b: G[n,i,e] = tf @ W3 for this i-quarter; 16 frag-cols per wave
  {
    short8 atf = *(const short8*)(TFl + l * TFS + q * 8);
    for (int t = 0; t < 16; ++t) {
      const int floc = (w * 16 + t) * 16 + l;            // local f in [0,1024)
      const int i = i0 + (floc >> 5), e = floc & 31;
      const float* wp = W_out + (size_t)i * 1024 + q * 8 * 32 + e;   // c = q*8+j, stride 32
      union { short8 s; unsigned u[4]; } bw;
      #pragma unroll
      for (int j = 0; j < 4; ++j)
        bw.u[j] = pack2(wp[(2 * j) * 32], wp[(2 * j + 1) * 32]);
      f32x4 d = __builtin_amdgcn_mfma_f32_16x16x32_bf16(atf, bw.s, zero, 0, 0, 0);
      const int ip = floc >> 5, e2 = floc & 31;
      #pragma unroll
      for (int r = 0; r < 4; ++r)
        U1.Gl[(q * 4 + r) * GSTR + ip * 32 + e2] = f2bf(d[r]);   // row n = q*4+r
    }
  }
  __syncthreads();   // Gl + DFb ready

  // ---- S6: out[b,n,m,i] tiles; A=G (M=i), B=df (N=m) -> float4 stores on i
  const float4 bo0 = *(const float4*)(b_out + i0 + q * 4);
  const float4 bo1 = *(const float4*)(b_out + i0 + 16 + q * 4);
  short8 bdf[4];
  float dm[4];
  #pragma unroll
  for (int mt = 0; mt < 4; ++mt) {
    bdf[mt] = *(const short8*)(DFb + (mt * 16 + l) * DFBS + q * 8);   // B[k=e][col=m]
    dm[mt] = dmask[b * 64 + mt * 16 + l];
  }
  for (int j = 0; j < 8; ++j) {
    const int p = w * 8 + j, n = p >> 1, it = p & 1;
    short8 ag = *(const short8*)(U1.Gl + n * GSTR + (it * 16 + l) * 32 + q * 8);  // A[i][e]
    const float tmv = tmask[b * 512 + n0 + n];
    const float4 bo = it ? bo1 : bo0;
    const size_t obase = ((size_t)(b * 512 + n0 + n) * 64) * 128 + (size_t)(i0 + it * 16 + q * 4);
    #pragma unroll
    for (int mt = 0; mt < 4; ++mt) {
      f32x4 d = __builtin_amdgcn_mfma_f32_16x16x32_bf16(ag, bdf[mt], zero, 0, 0, 0);
      const float s = tmv * dm[mt];
      float4 o;
      o.x = (d[0] + bo.x) * s; o.y = (d[1] + bo.y) * s;
      o.z = (d[2] + bo.z) * s; o.w = (d[3] + bo.w) * s;
      *(float4*)(out + obase + (size_t)(mt * 16 + l) * 128) = o;
    }
  }

  // ---- mask output: one iq-slice per (b, n16)
  if (iq == 0) {
    #pragma unroll
    for (int k = 0; k < 4; ++k) {
      const int t = tid + k * 256;           // 16 n x 64 m
      const int n = t >> 6, m = t & 63;
      mask_out[(size_t)(b * 512 + n0 + n) * 64 + m] =
          tmask[b * 512 + n0 + n] * dmask[b * 64 + m];
    }
  }
}

extern "C" void kernel_launch(void* const* d_in, const int* in_sizes, int n_in,
                              void* d_out, int out_size, void* d_ws, size_t ws_size,
                              hipStream_t stream)
{
  const float* tgt    = (const float*)d_in[0];
  const float* drg    = (const float*)d_in[1];
  const float* tmask  = (const float*)d_in[2];
  const float* dmask  = (const float*)d_in[3];
  const float* ln_t_g = (const float*)d_in[4];
  const float* ln_t_b = (const float*)d_in[5];
  const float* ln_d_g = (const float*)d_in[6];
  const float* ln_d_b = (const float*)d_in[7];
  const float* W_t    = (const float*)d_in[8];
  const float* b_t    = (const float*)d_in[9];
  const float* W_d    = (const float*)d_in[10];
  const float* b_d    = (const float*)d_in[11];
  const float* W_out  = (const float*)d_in[12];
  const float* b_out  = (const float*)d_in[13];

  float* out = (float*)d_out;
  float* mask_out = out + (size_t)4 * 512 * 64 * 128;   // second output

  k_fused<<<dim3(512), dim3(256), 0, stream>>>(
      tgt, drg, tmask, dmask, ln_t_g, ln_t_b, ln_d_g, ln_d_b,
      W_t, b_t, W_d, b_d, W_out, b_out, out, mask_out);
}

// Round 4
// 115.038 us; speedup vs baseline: 1.1166x; 1.1166x over previous
//
#include <hip/hip_runtime.h>

typedef __attribute__((ext_vector_type(8))) short short8;
typedef __attribute__((ext_vector_type(4))) float f32x4;

#define LNP_YSTRIDE 1032   // 16 rows x (1024+8) bf16
#define GSTR 1048          // G tile row stride (bf16 elems)

__device__ __forceinline__ unsigned short f2bf(float f) {
  union { float f; unsigned u; } v; v.f = f;
  unsigned r = v.u + 0x7FFFu + ((v.u >> 16) & 1u);  // RNE
  return (unsigned short)(r >> 16);
}
__device__ __forceinline__ unsigned pack2(float a, float b) {
  return (unsigned)f2bf(a) | ((unsigned)f2bf(b) << 16);
}
__device__ __forceinline__ short8 packW(float4 a, float4 b) {
  union { short8 s; unsigned u[4]; } r;
  r.u[0] = pack2(a.x, a.y); r.u[1] = pack2(a.z, a.w);
  r.u[2] = pack2(b.x, b.y); r.u[3] = pack2(b.z, b.w);
  return r.s;
}

// Fused LayerNorm + projection for a tile of 16 rows (R1 version — best measured).
template<int ROWLEN>
__device__ __forceinline__ void lnproj(
    const float* __restrict__ X, const float* __restrict__ g, const float* __restrict__ bia,
    const float* __restrict__ W, const float* __restrict__ pb, const float* __restrict__ msk,
    unsigned short* __restrict__ outb, int row0, unsigned short* Yl, float* pd, int tid)
{
  const int w = tid >> 6, lid = tid & 63, l = tid & 15, q = (tid >> 4) & 3;

  // ---- LayerNorm: wave w handles rows w*4 .. w*4+3, writes bf16 y to LDS
  #pragma unroll
  for (int rr = 0; rr < 4; ++rr) {
    const int row = w * 4 + rr;
    const float* xr = X + (size_t)(row0 + row) * ROWLEN;
    if (ROWLEN == 1024) {
      float4 v[4];
      float s = 0.f, s2 = 0.f;
      #pragma unroll
      for (int k = 0; k < 4; ++k) {
        v[k] = *(const float4*)(xr + 4 * lid + 256 * k);
        s  += (v[k].x + v[k].y) + (v[k].z + v[k].w);
        s2 += (v[k].x * v[k].x + v[k].y * v[k].y) + (v[k].z * v[k].z + v[k].w * v[k].w);
      }
      #pragma unroll
      for (int off = 32; off >= 1; off >>= 1) { s += __shfl_xor(s, off, 64); s2 += __shfl_xor(s2, off, 64); }
      const float mu = s * (1.f / 1024.f);
      const float rs = rsqrtf(s2 * (1.f / 1024.f) - mu * mu + 1e-5f);
      #pragma unroll
      for (int k = 0; k < 4; ++k) {
        float4 gg = *(const float4*)(g + 4 * lid + 256 * k);
        float4 bb = *(const float4*)(bia + 4 * lid + 256 * k);
        float y0 = (v[k].x - mu) * rs * gg.x + bb.x;
        float y1 = (v[k].y - mu) * rs * gg.y + bb.y;
        float y2 = (v[k].z - mu) * rs * gg.z + bb.z;
        float y3 = (v[k].w - mu) * rs * gg.w + bb.w;
        unsigned* yd = (unsigned*)(Yl + row * LNP_YSTRIDE + 4 * lid + 256 * k);
        yd[0] = pack2(y0, y1); yd[1] = pack2(y2, y3);
      }
    } else {  // ROWLEN == 128
      float2 v = *(const float2*)(xr + 2 * lid);
      float s = v.x + v.y, s2 = v.x * v.x + v.y * v.y;
      #pragma unroll
      for (int off = 32; off >= 1; off >>= 1) { s += __shfl_xor(s, off, 64); s2 += __shfl_xor(s2, off, 64); }
      const float mu = s * (1.f / 128.f);
      const float rs = rsqrtf(s2 * (1.f / 128.f) - mu * mu + 1e-5f);
      float2 gg = *(const float2*)(g + 2 * lid);
      float2 bb = *(const float2*)(bia + 2 * lid);
      *(unsigned*)(Yl + row * LNP_YSTRIDE + 2 * lid) =
          pack2((v.x - mu) * rs * gg.x + bb.x, (v.y - mu) * rs * gg.y + bb.y);
    }
  }
  __syncthreads();

  // ---- MFMA projection. wave w: h-tile ht = w&1, k-half kh = w>>1.
  const int KST = ROWLEN / 32;
  const int ht = w & 1, kh = w >> 1;
  const int h = ht * 16 + l;
  f32x4 acc = {0.f, 0.f, 0.f, 0.f};
  #pragma unroll
  for (int s = kh * (KST / 2); s < kh * (KST / 2) + KST / 2; ++s) {
    short8 af = *(const short8*)(Yl + l * LNP_YSTRIDE + s * 32 + q * 8);      // A[m=l][k]
    const float* wp = W + (size_t)h * ROWLEN + s * 32 + q * 8;                // B[k][n=h]
    short8 bf = packW(*(const float4*)wp, *(const float4*)(wp + 4));
    acc = __builtin_amdgcn_mfma_f32_16x16x32_bf16(af, bf, acc, 0, 0, 0);
  }
  if (w >= 2) {
    #pragma unroll
    for (int r = 0; r < 4; ++r) pd[ht * 256 + (q * 4 + r) * 16 + l] = acc[r];
  }
  __syncthreads();
  if (w < 2) {
    const float pbv = pb[h];
    #pragma unroll
    for (int r = 0; r < 4; ++r) {
      const int rg = row0 + q * 4 + r;                  // D row = quad*4+reg
      float val = acc[r] + pd[ht * 256 + (q * 4 + r) * 16 + l] + pbv;
      val *= msk[rg];
      outb[(size_t)rg * 32 + h] = f2bf(val);
    }
  }
}

// k_pre grid (280 blocks): [0,128) target LN+proj; [128,144) drug LN+proj;
// [144,152) W_out transpose -> W3pp[f=i*32+e][c] bf16; [152,280) mask output.
__global__ __launch_bounds__(256) void k_pre(
    const float* __restrict__ tgt, const float* __restrict__ drg,
    const float* __restrict__ tmask, const float* __restrict__ dmask,
    const float* __restrict__ ln_t_g, const float* __restrict__ ln_t_b,
    const float* __restrict__ ln_d_g, const float* __restrict__ ln_d_b,
    const float* __restrict__ W_t, const float* __restrict__ b_t,
    const float* __restrict__ W_d, const float* __restrict__ b_d,
    const float* __restrict__ W_out,
    unsigned short* __restrict__ w3pp, unsigned short* __restrict__ tfb,
    unsigned short* __restrict__ dfb, float* __restrict__ mask_out)
{
  __shared__ unsigned short Yl[16 * LNP_YSTRIDE];
  __shared__ float pd[2 * 16 * 16];
  const int blk = blockIdx.x, tid = threadIdx.x;
  if (blk < 128) {
    lnproj<1024>(tgt, ln_t_g, ln_t_b, W_t, b_t, tmask, tfb, blk * 16, Yl, pd, tid);
  } else if (blk < 144) {
    lnproj<128>(drg, ln_d_g, ln_d_b, W_d, b_d, dmask, dfb, (blk - 128) * 16, Yl, pd, tid);
  } else if (blk < 152) {
    const int tg = (blk - 144) * 256 + tid;
    #pragma unroll
    for (int rep = 0; rep < 2; ++rep) {
      const int f = tg + rep * 2048;
      const int i = f >> 5, e = f & 31;
      unsigned short us[32];
      #pragma unroll
      for (int c = 0; c < 32; ++c) us[c] = f2bf(W_out[i * 1024 + c * 32 + e]);
      unsigned* dst = (unsigned*)(w3pp + (size_t)f * 32);
      #pragma unroll
      for (int j = 0; j < 16; ++j) dst[j] = (unsigned)us[2 * j] | ((unsigned)us[2 * j + 1] << 16);
    }
  } else {
    const int base = ((blk - 152) * 256 + tid) * 4;   // flat index into [4,512,64]
    const int b = base >> 15;
    const float tm = tmask[base >> 6];
    float4 d = *(const float4*)(dmask + b * 64 + (base & 63));
    float4 o; o.x = tm * d.x; o.y = tm * d.y; o.z = tm * d.z; o.w = tm * d.w;
    *(float4*)(mask_out + base) = o;
  }
}

// k_main: 512 blocks = b(4) x n-tile16(32) x i-quarter(4).
// Phase 1: G[n,i,e] = sum_c tf[n,c] * W3pp[i*32+e][c]  (MFMA, D -> LDS bf16)
// Phase 2: A=G (M=i), B=df (N=m)  ->  D rows = consecutive i  ->  float4 stores.
__global__ __launch_bounds__(256) void k_main(
    const unsigned short* __restrict__ w3pp, const unsigned short* __restrict__ tfb,
    const unsigned short* __restrict__ dfb, const float* __restrict__ b_out,
    const float* __restrict__ tmask, const float* __restrict__ dmask,
    float* __restrict__ out)
{
  __shared__ unsigned short Gl[16 * GSTR];   // 33.5 KB
  const int id = blockIdx.x;
  const int b = id >> 7, n16 = (id >> 2) & 31, iq = id & 3;
  const int n0 = n16 * 16, i0 = iq * 32;
  const int tid = threadIdx.x, w = tid >> 6, l = tid & 15, q = (tid >> 4) & 3;

  // tf A-fragment (phase 1); df B-fragments per m-tile (phase 2; B[k=e][col=m=l])
  short8 atf = *(const short8*)(tfb + (size_t)(b * 512 + n0 + l) * 32 + q * 8);
  short8 bdf[4];
  #pragma unroll
  for (int mt = 0; mt < 4; ++mt)
    bdf[mt] = *(const short8*)(dfb + (size_t)(b * 64 + mt * 16 + l) * 32 + q * 8);

  const f32x4 zero = {0.f, 0.f, 0.f, 0.f};

  // ---- Phase 1: 64 col-tiles (flat f = i*32+e over this i-quarter), 16 per wave
  for (int t = w * 16; t < w * 16 + 16; ++t) {
    const int f = i0 * 32 + t * 16 + l;
    short8 bw = *(const short8*)(w3pp + (size_t)f * 32 + q * 8);   // B[c][f]
    f32x4 d = __builtin_amdgcn_mfma_f32_16x16x32_bf16(atf, bw, zero, 0, 0, 0);
    const int floc = t * 16 + l, ip = floc >> 5, e = floc & 31;
    #pragma unroll
    for (int r = 0; r < 4; ++r)
      Gl[(q * 4 + r) * GSTR + ip * 32 + e] = f2bf(d[r]);   // row n = q*4+r
  }
  __syncthreads();

  const float4 bo0 = *(const float4*)(b_out + i0 + q * 4);
  const float4 bo1 = *(const float4*)(b_out + i0 + 16 + q * 4);
  float dm[4];
  #pragma unroll
  for (int mt = 0; mt < 4; ++mt) dm[mt] = dmask[b * 64 + mt * 16 + l];

  // ---- Phase 2: wave handles 4 n x 2 i-tiles x 4 m-tiles = 32 MFMAs
  for (int j = 0; j < 8; ++j) {
    const int p = w * 8 + j, n = p >> 1, it = p & 1;
    // A[row=i][k=e] = G[n][i][e]: lane l -> i_loc = it*16+l, e-chunk q*8
    short8 ag = *(const short8*)(Gl + n * GSTR + (it * 16 + l) * 32 + q * 8);
    const float tmv = tmask[b * 512 + n0 + n];
    const float4 bo = it ? bo1 : bo0;
    const size_t obase = ((size_t)(b * 512 + n0 + n) * 64) * 128 + (size_t)(i0 + it * 16 + q * 4);
    #pragma unroll
    for (int mt = 0; mt < 4; ++mt) {
      f32x4 d = __builtin_amdgcn_mfma_f32_16x16x32_bf16(ag, bdf[mt], zero, 0, 0, 0);
      const float s = tmv * dm[mt];
      float4 o;
      o.x = (d[0] + bo.x) * s; o.y = (d[1] + bo.y) * s;
      o.z = (d[2] + bo.z) * s; o.w = (d[3] + bo.w) * s;
      *(float4*)(out + obase + (size_t)(mt * 16 + l) * 128) = o;   // i = q*4 + 0..3
    }
  }
}

extern "C" void kernel_launch(void* const* d_in, const int* in_sizes, int n_in,
                              void* d_out, int out_size, void* d_ws, size_t ws_size,
                              hipStream_t stream)
{
  const float* tgt    = (const float*)d_in[0];
  const float* drg    = (const float*)d_in[1];
  const float* tmask  = (const float*)d_in[2];
  const float* dmask  = (const float*)d_in[3];
  const float* ln_t_g = (const float*)d_in[4];
  const float* ln_t_b = (const float*)d_in[5];
  const float* ln_d_g = (const float*)d_in[6];
  const float* ln_d_b = (const float*)d_in[7];
  const float* W_t    = (const float*)d_in[8];
  const float* b_t    = (const float*)d_in[9];
  const float* W_d    = (const float*)d_in[10];
  const float* b_d    = (const float*)d_in[11];
  const float* W_out  = (const float*)d_in[12];
  const float* b_out  = (const float*)d_in[13];

  float* out = (float*)d_out;
  float* mask_out = out + (size_t)4 * 512 * 64 * 128;   // second output

  char* ws = (char*)d_ws;
  unsigned short* w3pp = (unsigned short*)(ws);                    // 4096*32 bf16 = 256 KB
  unsigned short* tfb  = (unsigned short*)(ws + 262144);           // 2048*32 bf16 = 128 KB
  unsigned short* dfb  = (unsigned short*)(ws + 262144 + 131072);  // 256*32 bf16 = 16 KB

  k_pre<<<dim3(280), dim3(256), 0, stream>>>(
      tgt, drg, tmask, dmask, ln_t_g, ln_t_b, ln_d_g, ln_d_b,
      W_t, b_t, W_d, b_d, W_out, w3pp, tfb, dfb, mask_out);
  k_main<<<dim3(512), dim3(256), 0, stream>>>(
      w3pp, tfb, dfb, b_out, tmask, dmask, out);
}

// Round 5
// 113.460 us; speedup vs baseline: 1.1321x; 1.0139x over previous
//
#include <hip/hip_runtime.h>

typedef __attribute__((ext_vector_type(8))) short short8;
typedef __attribute__((ext_vector_type(4))) float f32x4;

#define LNP_YSTRIDE 1032   // 16 rows x (1024+8) bf16
#define GSTR 1048          // G tile row stride (bf16 elems)

__device__ __forceinline__ unsigned short f2bf(float f) {
  union { float f; unsigned u; } v; v.f = f;
  unsigned r = v.u + 0x7FFFu + ((v.u >> 16) & 1u);  // RNE
  return (unsigned short)(r >> 16);
}
__device__ __forceinline__ unsigned pack2(float a, float b) {
  return (unsigned)f2bf(a) | ((unsigned)f2bf(b) << 16);
}
__device__ __forceinline__ short8 packW(float4 a, float4 b) {
  union { short8 s; unsigned u[4]; } r;
  r.u[0] = pack2(a.x, a.y); r.u[1] = pack2(a.z, a.w);
  r.u[2] = pack2(b.x, b.y); r.u[3] = pack2(b.z, b.w);
  return r.s;
}

// 8-row target LN + projection: 256 blocks. Wave w LNs rows w*2..w*2+1;
// MFMA K=1024 split 4 ways (wave w: k-steps w*8..w*8+7), both h-tiles per wave.
// A rows 8..15 are uninitialized LDS — D rows are independent; only rows 0..7 stored.
__device__ __forceinline__ void lnproj8_t(
    const float* __restrict__ X, const float* __restrict__ g, const float* __restrict__ bia,
    const float* __restrict__ W, const float* __restrict__ pb, const float* __restrict__ msk,
    unsigned short* __restrict__ outb, int row0, unsigned short* Yl, float* pd, int tid)
{
  const int w = tid >> 6, lid = tid & 63, l = tid & 15, q = (tid >> 4) & 3;
  const f32x4 zero = {0.f, 0.f, 0.f, 0.f};

  #pragma unroll
  for (int rr = 0; rr < 2; ++rr) {
    const int row = w * 2 + rr;
    const float* xr = X + (size_t)(row0 + row) * 1024;
    float4 v[4];
    float s = 0.f, s2 = 0.f;
    #pragma unroll
    for (int k = 0; k < 4; ++k) {
      v[k] = *(const float4*)(xr + 4 * lid + 256 * k);
      s  += (v[k].x + v[k].y) + (v[k].z + v[k].w);
      s2 += (v[k].x * v[k].x + v[k].y * v[k].y) + (v[k].z * v[k].z + v[k].w * v[k].w);
    }
    #pragma unroll
    for (int off = 32; off >= 1; off >>= 1) { s += __shfl_xor(s, off, 64); s2 += __shfl_xor(s2, off, 64); }
    const float mu = s * (1.f / 1024.f);
    const float rs = rsqrtf(s2 * (1.f / 1024.f) - mu * mu + 1e-5f);
    #pragma unroll
    for (int k = 0; k < 4; ++k) {
      float4 gg = *(const float4*)(g + 4 * lid + 256 * k);
      float4 bb = *(const float4*)(bia + 4 * lid + 256 * k);
      unsigned* yd = (unsigned*)(Yl + row * LNP_YSTRIDE + 4 * lid + 256 * k);
      yd[0] = pack2((v[k].x - mu) * rs * gg.x + bb.x, (v[k].y - mu) * rs * gg.y + bb.y);
      yd[1] = pack2((v[k].z - mu) * rs * gg.z + bb.z, (v[k].w - mu) * rs * gg.w + bb.w);
    }
  }
  __syncthreads();

  // MFMA: wave w takes k-steps w*8..w*8+7 for BOTH h-tiles (h=l and h=16+l)
  f32x4 acc0 = zero, acc1 = zero;
  #pragma unroll
  for (int ss = 0; ss < 8; ++ss) {
    const int s = w * 8 + ss;
    short8 af = *(const short8*)(Yl + l * LNP_YSTRIDE + s * 32 + q * 8);   // A[m][k]
    const float* wp0 = W + (size_t)l * 1024 + s * 32 + q * 8;              // h = l
    const float* wp1 = W + (size_t)(16 + l) * 1024 + s * 32 + q * 8;       // h = 16+l
    acc0 = __builtin_amdgcn_mfma_f32_16x16x32_bf16(af, packW(*(const float4*)wp0, *(const float4*)(wp0 + 4)), acc0, 0, 0, 0);
    acc1 = __builtin_amdgcn_mfma_f32_16x16x32_bf16(af, packW(*(const float4*)wp1, *(const float4*)(wp1 + 4)), acc1, 0, 0, 0);
  }
  if (w > 0 && q < 2) {
    #pragma unroll
    for (int r = 0; r < 4; ++r) {
      const int rl = q * 4 + r;                        // D row 0..7
      pd[(w - 1) * 256 + rl * 16 + l]       = acc0[r];
      pd[(w - 1) * 256 + 128 + rl * 16 + l] = acc1[r];
    }
  }
  __syncthreads();
  if (w == 0 && q < 2) {
    #pragma unroll
    for (int ht = 0; ht < 2; ++ht) {
      const int h = ht * 16 + l;
      const float pbv = pb[h];
      #pragma unroll
      for (int r = 0; r < 4; ++r) {
        const int rl = q * 4 + r, rg = row0 + rl;
        float val = (ht ? acc1[r] : acc0[r]) + pbv;
        #pragma unroll
        for (int k = 0; k < 3; ++k) val += pd[k * 256 + ht * 128 + rl * 16 + l];
        outb[(size_t)rg * 32 + h] = f2bf(val * msk[rg]);
      }
    }
  }
}

// 16-row LN+proj (R4 version) — used for the drug side (ROWLEN=128).
template<int ROWLEN>
__device__ __forceinline__ void lnproj(
    const float* __restrict__ X, const float* __restrict__ g, const float* __restrict__ bia,
    const float* __restrict__ W, const float* __restrict__ pb, const float* __restrict__ msk,
    unsigned short* __restrict__ outb, int row0, unsigned short* Yl, float* pd, int tid)
{
  const int w = tid >> 6, lid = tid & 63, l = tid & 15, q = (tid >> 4) & 3;

  #pragma unroll
  for (int rr = 0; rr < 4; ++rr) {
    const int row = w * 4 + rr;
    const float* xr = X + (size_t)(row0 + row) * ROWLEN;
    float2 v = *(const float2*)(xr + 2 * lid);
    float s = v.x + v.y, s2 = v.x * v.x + v.y * v.y;
    #pragma unroll
    for (int off = 32; off >= 1; off >>= 1) { s += __shfl_xor(s, off, 64); s2 += __shfl_xor(s2, off, 64); }
    const float mu = s * (1.f / ROWLEN);
    const float rs = rsqrtf(s2 * (1.f / ROWLEN) - mu * mu + 1e-5f);
    float2 gg = *(const float2*)(g + 2 * lid);
    float2 bb = *(const float2*)(bia + 2 * lid);
    *(unsigned*)(Yl + row * LNP_YSTRIDE + 2 * lid) =
        pack2((v.x - mu) * rs * gg.x + bb.x, (v.y - mu) * rs * gg.y + bb.y);
  }
  __syncthreads();

  const int KST = ROWLEN / 32;
  const int ht = w & 1, kh = w >> 1;
  const int h = ht * 16 + l;
  f32x4 acc = {0.f, 0.f, 0.f, 0.f};
  #pragma unroll
  for (int s = kh * (KST / 2); s < kh * (KST / 2) + KST / 2; ++s) {
    short8 af = *(const short8*)(Yl + l * LNP_YSTRIDE + s * 32 + q * 8);
    const float* wp = W + (size_t)h * ROWLEN + s * 32 + q * 8;
    short8 bf = packW(*(const float4*)wp, *(const float4*)(wp + 4));
    acc = __builtin_amdgcn_mfma_f32_16x16x32_bf16(af, bf, acc, 0, 0, 0);
  }
  if (w >= 2) {
    #pragma unroll
    for (int r = 0; r < 4; ++r) pd[ht * 256 + (q * 4 + r) * 16 + l] = acc[r];
  }
  __syncthreads();
  if (w < 2) {
    const float pbv = pb[h];
    #pragma unroll
    for (int r = 0; r < 4; ++r) {
      const int rg = row0 + q * 4 + r;
      float val = acc[r] + pd[ht * 256 + (q * 4 + r) * 16 + l] + pbv;
      val *= msk[rg];
      outb[(size_t)rg * 32 + h] = f2bf(val);
    }
  }
}

// k_pre grid (408 blocks): [0,256) target LN+proj (8 rows);
// [256,272) drug LN+proj (16 rows); [272,280) W_out transpose; [280,408) mask out.
__global__ __launch_bounds__(256) void k_pre(
    const float* __restrict__ tgt, const float* __restrict__ drg,
    const float* __restrict__ tmask, const float* __restrict__ dmask,
    const float* __restrict__ ln_t_g, const float* __restrict__ ln_t_b,
    const float* __restrict__ ln_d_g, const float* __restrict__ ln_d_b,
    const float* __restrict__ W_t, const float* __restrict__ b_t,
    const float* __restrict__ W_d, const float* __restrict__ b_d,
    const float* __restrict__ W_out,
    unsigned short* __restrict__ w3pp, unsigned short* __restrict__ tfb,
    unsigned short* __restrict__ dfb, float* __restrict__ mask_out)
{
  __shared__ unsigned short Yl[16 * LNP_YSTRIDE];
  __shared__ float pd[3 * 256];
  const int blk = blockIdx.x, tid = threadIdx.x;
  if (blk < 256) {
    lnproj8_t(tgt, ln_t_g, ln_t_b, W_t, b_t, tmask, tfb, blk * 8, Yl, pd, tid);
  } else if (blk < 272) {
    lnproj<128>(drg, ln_d_g, ln_d_b, W_d, b_d, dmask, dfb, (blk - 256) * 16, Yl, pd, tid);
  } else if (blk < 280) {
    const int tg = (blk - 272) * 256 + tid;
    #pragma unroll
    for (int rep = 0; rep < 2; ++rep) {
      const int f = tg + rep * 2048;
      const int i = f >> 5, e = f & 31;
      unsigned short us[32];
      #pragma unroll
      for (int c = 0; c < 32; ++c) us[c] = f2bf(W_out[i * 1024 + c * 32 + e]);
      unsigned* dst = (unsigned*)(w3pp + (size_t)f * 32);
      #pragma unroll
      for (int j = 0; j < 16; ++j) dst[j] = (unsigned)us[2 * j] | ((unsigned)us[2 * j + 1] << 16);
    }
  } else {
    const int base = ((blk - 280) * 256 + tid) * 4;   // flat index into [4,512,64]
    const int b = base >> 15;
    const float tm = tmask[base >> 6];
    float4 d = *(const float4*)(dmask + b * 64 + (base & 63));
    float4 o; o.x = tm * d.x; o.y = tm * d.y; o.z = tm * d.z; o.w = tm * d.w;
    *(float4*)(mask_out + base) = o;
  }
}

// k_main (R4 — best measured): 512 blocks = b(4) x n-tile16(32) x i-quarter(4).
__global__ __launch_bounds__(256) void k_main(
    const unsigned short* __restrict__ w3pp, const unsigned short* __restrict__ tfb,
    const unsigned short* __restrict__ dfb, const float* __restrict__ b_out,
    const float* __restrict__ tmask, const float* __restrict__ dmask,
    float* __restrict__ out)
{
  __shared__ unsigned short Gl[16 * GSTR];   // 33.5 KB
  const int id = blockIdx.x;
  const int b = id >> 7, n16 = (id >> 2) & 31, iq = id & 3;
  const int n0 = n16 * 16, i0 = iq * 32;
  const int tid = threadIdx.x, w = tid >> 6, l = tid & 15, q = (tid >> 4) & 3;

  short8 atf = *(const short8*)(tfb + (size_t)(b * 512 + n0 + l) * 32 + q * 8);
  short8 bdf[4];
  #pragma unroll
  for (int mt = 0; mt < 4; ++mt)
    bdf[mt] = *(const short8*)(dfb + (size_t)(b * 64 + mt * 16 + l) * 32 + q * 8);

  const f32x4 zero = {0.f, 0.f, 0.f, 0.f};

  // Phase 1: G[n,i,e] = tf @ W3 for this i-quarter (16 frag-cols per wave)
  for (int t = w * 16; t < w * 16 + 16; ++t) {
    const int f = i0 * 32 + t * 16 + l;
    short8 bw = *(const short8*)(w3pp + (size_t)f * 32 + q * 8);   // B[c][f]
    f32x4 d = __builtin_amdgcn_mfma_f32_16x16x32_bf16(atf, bw, zero, 0, 0, 0);
    const int floc = t * 16 + l, ip = floc >> 5, e = floc & 31;
    #pragma unroll
    for (int r = 0; r < 4; ++r)
      Gl[(q * 4 + r) * GSTR + ip * 32 + e] = f2bf(d[r]);   // row n = q*4+r
  }
  __syncthreads();

  const float4 bo0 = *(const float4*)(b_out + i0 + q * 4);
  const float4 bo1 = *(const float4*)(b_out + i0 + 16 + q * 4);
  float dm[4];
  #pragma unroll
  for (int mt = 0; mt < 4; ++mt) dm[mt] = dmask[b * 64 + mt * 16 + l];

  // Phase 2: A=G (M=i), B=df (N=m) -> D rows consecutive i -> float4 stores
  for (int j = 0; j < 8; ++j) {
    const int p = w * 8 + j, n = p >> 1, it = p & 1;
    short8 ag = *(const short8*)(Gl + n * GSTR + (it * 16 + l) * 32 + q * 8);
    const float tmv = tmask[b * 512 + n0 + n];
    const float4 bo = it ? bo1 : bo0;
    const size_t obase = ((size_t)(b * 512 + n0 + n) * 64) * 128 + (size_t)(i0 + it * 16 + q * 4);
    #pragma unroll
    for (int mt = 0; mt < 4; ++mt) {
      f32x4 d = __builtin_amdgcn_mfma_f32_16x16x32_bf16(ag, bdf[mt], zero, 0, 0, 0);
      const float s = tmv * dm[mt];
      float4 o;
      o.x = (d[0] + bo.x) * s; o.y = (d[1] + bo.y) * s;
      o.z = (d[2] + bo.z) * s; o.w = (d[3] + bo.w) * s;
      *(float4*)(out + obase + (size_t)(mt * 16 + l) * 128) = o;
    }
  }
}

extern "C" void kernel_launch(void* const* d_in, const int* in_sizes, int n_in,
                              void* d_out, int out_size, void* d_ws, size_t ws_size,
                              hipStream_t stream)
{
  const float* tgt    = (const float*)d_in[0];
  const float* drg    = (const float*)d_in[1];
  const float* tmask  = (const float*)d_in[2];
  const float* dmask  = (const float*)d_in[3];
  const float* ln_t_g = (const float*)d_in[4];
  const float* ln_t_b = (const float*)d_in[5];
  const float* ln_d_g = (const float*)d_in[6];
  const float* ln_d_b = (const float*)d_in[7];
  const float* W_t    = (const float*)d_in[8];
  const float* b_t    = (const float*)d_in[9];
  const float* W_d    = (const float*)d_in[10];
  const float* b_d    = (const float*)d_in[11];
  const float* W_out  = (const float*)d_in[12];
  const float* b_out  = (const float*)d_in[13];

  float* out = (float*)d_out;
  float* mask_out = out + (size_t)4 * 512 * 64 * 128;   // second output

  char* ws = (char*)d_ws;
  unsigned short* w3pp = (unsigned short*)(ws);                    // 4096*32 bf16 = 256 KB
  unsigned short* tfb  = (unsigned short*)(ws + 262144);           // 2048*32 bf16 = 128 KB
  unsigned short* dfb  = (unsigned short*)(ws + 262144 + 131072);  // 256*32 bf16 = 16 KB

  k_pre<<<dim3(408), dim3(256), 0, stream>>>(
      tgt, drg, tmask, dmask, ln_t_g, ln_t_b, ln_d_g, ln_d_b,
      W_t, b_t, W_d, b_d, W_out, w3pp, tfb, dfb, mask_out);
  k_main<<<dim3(512), dim3(256), 0, stream>>>(
      w3pp, tfb, dfb, b_out, tmask, dmask, out);
}